// Round 10
// baseline (3377.419 us; speedup 1.0000x reference)
//
#include <hip/hip_runtime.h>
#include <math.h>

// Problem constants: L=512 (batch/spatial), T=96, C=H=150, K=5
#define LB     512
#define TSTEPS 96
#define CIN    150
#define HDIM   150
#define KW     5
#define CO3    450   // 3*H
// gru tiling
#define NBT    16    // b-tiles
#define NJT    15    // j-tiles
#define BROWS  32    // rows per b-tile
#define JW     10    // j per j-tile (30 co = 3 gates x 10 j)
#define NCH    15    // ci chunks
#define CICH   10    // ci per chunk
#define HROWS  36    // staged rows = 32 + 2x2 halo
#define HPAD   152   // LDS row stride (floats)
#define CNTSTR 32    // ints per counter slot (128 B)
#define PARTR  33    // padded row dim of part (990%32=30: keeps ch in bank idx)
#define STIT   6     // ceil(HROWS*CIN / 1024)

// fast device math: v_exp_f32-based sigmoid / tanh (rel err ~2^-21)
__device__ __forceinline__ float fsigmoid(float x) {
    return __builtin_amdgcn_rcpf(1.f + __expf(-x));
}
__device__ __forceinline__ float ftanh(float x) {
    return fmaf(2.f, __builtin_amdgcn_rcpf(1.f + __expf(-2.f * x)), -1.f);
}

// coherent (agent-scope) ops for cross-XCD h traffic; ordering via the
// producer-side __syncthreads vmcnt(0) drain before the flag add.
__device__ __forceinline__ float h_load(const float* p) {
    return __hip_atomic_load(p, __ATOMIC_RELAXED, __HIP_MEMORY_SCOPE_AGENT);
}
__device__ __forceinline__ void h_store(float* p, float v) {
    __hip_atomic_store(p, v, __ATOMIC_RELAXED, __HIP_MEMORY_SCOPE_AGENT);
}

// ---------------------------------------------------------------------------
// xi conv (unchanged; measured 445 us, VALUBusy 81%, ~74 TF)
// ---------------------------------------------------------------------------
__global__ __launch_bounds__(256) void xi_conv_kernel(
    const float* __restrict__ src, long srcB, long srcT,
    const float* __restrict__ Wi, const float* __restrict__ bias,
    float* __restrict__ xi)
{
    __shared__ __align__(16) float xsh[CIN][20];
    const int b0  = blockIdx.x * 16;
    const int t   = blockIdx.y;
    const int tid = threadIdx.x;

    for (int idx = tid; idx < 20 * CIN; idx += 256) {
        int row = idx / CIN;
        int ci  = idx - row * CIN;
        int bp  = b0 + row - 2;
        float v = 0.f;
        if (bp >= 0 && bp < LB) v = src[(long)bp * srcB + (long)t * srcT + ci];
        xsh[ci][row] = v;
    }
    __syncthreads();

    if (tid < 225) {
        const int co = 2 * tid;
        float acc0[16], acc1[16];
        #pragma unroll
        for (int b = 0; b < 16; ++b) { acc0[b] = 0.f; acc1[b] = 0.f; }

        for (int ci = 0; ci < CIN; ++ci) {
            float4 a0 = *(const float4*)&xsh[ci][0];
            float4 a1 = *(const float4*)&xsh[ci][4];
            float4 a2 = *(const float4*)&xsh[ci][8];
            float4 a3 = *(const float4*)&xsh[ci][12];
            float4 a4 = *(const float4*)&xsh[ci][16];
            float xr[20];
            xr[0]=a0.x; xr[1]=a0.y; xr[2]=a0.z; xr[3]=a0.w;
            xr[4]=a1.x; xr[5]=a1.y; xr[6]=a1.z; xr[7]=a1.w;
            xr[8]=a2.x; xr[9]=a2.y; xr[10]=a2.z; xr[11]=a2.w;
            xr[12]=a3.x; xr[13]=a3.y; xr[14]=a3.z; xr[15]=a3.w;
            xr[16]=a4.x; xr[17]=a4.y; xr[18]=a4.z; xr[19]=a4.w;

            #pragma unroll
            for (int k = 0; k < KW; ++k) {
                const float2 w = *(const float2*)&Wi[((long)(k * CIN + ci)) * CO3 + co];
                #pragma unroll
                for (int b = 0; b < 16; ++b) {
                    float x = xr[b + k];
                    acc0[b] = fmaf(w.x, x, acc0[b]);
                    acc1[b] = fmaf(w.y, x, acc1[b]);
                }
            }
        }

        const float2 bia = *(const float2*)&bias[co];
        float* xo = xi + ((long)t * LB + b0) * CO3 + co;
        #pragma unroll
        for (int b = 0; b < 16; ++b) {
            float2 o; o.x = acc0[b] + bia.x; o.y = acc1[b] + bia.y;
            *(float2*)&xo[(long)b * CO3] = o;
        }
    }
}

// ---------------------------------------------------------------------------
// Persistent GRU pipeline — round-8 structure (best: 10.4 us/step) at 2x
// occupancy: 1024 threads = 16 waves/CU (4/SIMD) for latency hiding.
// Conv thread owns 16 rows (two 450-thread row-groups rg=0/1); summation
// order bitwise-identical to round 8 (absmax canary: 0.00390625).
//   P0 parallel 3-way poll -> P1 xi prefetch + stage 36 rows (6x1024, all
//   loads in flight) -> P2 conv (acc[16]) -> P3 reduce 15 chunks + gates
//   -> store h(t) (agent-scope) -> flag++.
// ---------------------------------------------------------------------------
__global__ __launch_bounds__(1024, 4) void gru_seq_kernel(
    const float* __restrict__ Wh,
    const float* __restrict__ xi,
    float* __restrict__ ybase,
    long yT, long bS,
    int* __restrict__ cnt)
{
    __shared__ __align__(16) float hsh[HROWS][HPAD];      // 21.9 KB [row][ci]
    __shared__ float part[NCH][PARTR][3 * JW];            // 59.4 KB

    const int blk = blockIdx.x;
    const int bt  = blk / NJT;
    const int jt  = blk - bt * NJT;
    const int b0  = bt * BROWS;
    const int j0  = jt * JW;
    const int tid = threadIdx.x;

    const int  rg  = tid >> 9;               // row-group 0/1 (16 rows each)
    const int  tl  = tid & 511;
    const bool act = (tl < NCH * 3 * JW);    // 450 conv threads per group
    const int  c   = tl % (3 * JW);
    const int  ch  = tl / (3 * JW);
    const int  g   = c / JW;
    const int  jl  = c - g * JW;
    const int  co  = g * HDIM + j0 + jl;
    const int  ci0 = ch * CICH;
    const int  rbase = rg * 16;              // this thread's output rows

    const bool gthr = (tid < BROWS * JW);    // 320 gate threads
    const int  grow = tid / JW;
    const int  gj   = tid - grow * JW;

    // ---- one-time: weights into registers ----
    float w[KW][CICH];
    if (act) {
        #pragma unroll
        for (int k = 0; k < KW; ++k)
            #pragma unroll
            for (int i = 0; i < CICH; ++i)
                w[k][i] = Wh[((long)(k * CIN + ci0 + i)) * CO3 + co];
    }

    for (int t = 0; t < TSTEPS; ++t) {
        // ---- P0: 3-way parallel poll of producer flags (bt-1, bt, bt+1) ----
        if (t > 0 && tid < 3) {
            int x = bt - 1 + tid;
            if (x >= 0 && x < NBT) {
                const int tgt = NJT * t;
                while (__hip_atomic_load(&cnt[x * CNTSTR], __ATOMIC_RELAXED,
                                         __HIP_MEMORY_SCOPE_AGENT) < tgt)
                    __builtin_amdgcn_s_sleep(1);
            }
        }
        __syncthreads();

        // ---- P1: xi prefetch (consumed in gates ~8us later) ----
        float pxr = 0.f, pxz = 0.f, pxn = 0.f;
        if (gthr) {
            const float* xp = xi + ((long)t * LB + b0 + grow) * CO3 + j0 + gj;
            pxr = xp[0];
            pxz = xp[HDIM];
            pxn = xp[2 * HDIM];
        }

        // ---- stage h(t-1) rows b0-2..b0+33: fully unrolled, loads in flight ----
        if (t > 0) {
            const float* hsrc = ybase + (long)(t - 1) * yT;
            float v[STIT];
            int   rw[STIT], cv[STIT];
            bool  ok[STIT];
            #pragma unroll
            for (int it = 0; it < STIT; ++it) {
                int idx = tid + it * 1024;
                int idc = (idx < HROWS * CIN) ? idx : (HROWS * CIN - 1);
                int row = idc / CIN, ci = idc - row * CIN;
                int gr  = b0 - 2 + row;
                ok[it]  = (idx < HROWS * CIN) && (gr >= 0) && (gr < LB);
                int grc = gr < 0 ? 0 : (gr > LB - 1 ? LB - 1 : gr);
                v[it]   = h_load(&hsrc[(long)grc * bS + ci]);  // clamped: in-range
                rw[it]  = row; cv[it] = ci;
            }
            #pragma unroll
            for (int it = 0; it < STIT; ++it) {
                if (tid + it * 1024 < HROWS * CIN)
                    hsh[rw[it]][cv[it]] = ok[it] ? v[it] : 0.f;
            }
        } else {
            for (int idx = tid; idx < HROWS * CIN; idx += 1024)
                hsh[idx / CIN][idx % CIN] = 0.f;
        }
        __syncthreads();

        // ---- P2: conv — acc[rl] += w[k][i]*staged[rbase+rl+k][ci0+i] ----
        if (act) {
            float acc[16];
            #pragma unroll
            for (int r = 0; r < 16; ++r) acc[r] = 0.f;
            #pragma unroll
            for (int p = 0; p < CICH / 2; ++p) {
                #pragma unroll
                for (int row = 0; row < 20; ++row) {       // staged rows rbase..rbase+19
                    float2 h2 = *(const float2*)&hsh[rbase + row][ci0 + 2 * p];
                    #pragma unroll
                    for (int k = 0; k < KW; ++k) {
                        const int rl = row - k;            // output row rbase+rl
                        if (rl >= 0 && rl < 16) {
                            acc[rl] = fmaf(w[k][2 * p],     h2.x, acc[rl]);
                            acc[rl] = fmaf(w[k][2 * p + 1], h2.y, acc[rl]);
                        }
                    }
                }
            }
            #pragma unroll
            for (int rl = 0; rl < 16; ++rl) part[ch][rbase + rl][c] = acc[rl];
        }
        __syncthreads();

        // ---- P3: reduce 15 chunks + gates (prefetched xi) + coherent store ----
        if (gthr) {
            float hr = 0.f, hz = 0.f, hn = 0.f;
            #pragma unroll
            for (int s = 0; s < NCH; ++s) {
                hr += part[s][grow][gj];
                hz += part[s][grow][JW + gj];
                hn += part[s][grow][2 * JW + gj];
            }
            const int b = b0 + grow;
            float r  = fsigmoid(pxr + hr);
            float z  = fsigmoid(pxz + hz);
            float n  = ftanh(fmaf(r, hn, pxn));
            float hp = hsh[grow + 2][j0 + gj];       // h(t-1)[b][j], zeros at t=0
            h_store(&ybase[(long)t * yT + (long)b * bS + j0 + gj],
                    fmaf(z, hp - n, n));
        }
        __syncthreads();   // drains vmcnt(0): h(t) stores acked before flag add

        if (tid == 0)
            __hip_atomic_fetch_add(&cnt[bt * CNTSTR], 1, __ATOMIC_RELAXED,
                                   __HIP_MEMORY_SCOPE_AGENT);
    }
}

// ---------------------------------------------------------------------------
__global__ void zero_cnt_kernel(int* cnt) {
    for (int i = threadIdx.x; i < 2 * NBT * CNTSTR; i += 256) cnt[i] = 0;
}

// ---------------------------------------------------------------------------
extern "C" void kernel_launch(void* const* d_in, const int* in_sizes, int n_in,
                              void* d_out, int out_size, void* d_ws, size_t ws_size,
                              hipStream_t stream) {
    const float* xs  = (const float*)d_in[0];
    const float* Wi0 = (const float*)d_in[1];
    const float* bi0 = (const float*)d_in[2];
    const float* Wh0 = (const float*)d_in[3];
    const float* Wi1 = (const float*)d_in[4];
    const float* bi1 = (const float*)d_in[5];
    const float* Wh1 = (const float*)d_in[6];
    float* out = (float*)d_out;

    // ws layout: [cnt 2*16*128B = 4 KB | xi 88.5 MB | ys0 29.5 MB]
    int*   cnt = (int*)d_ws;
    float* xi  = (float*)((char*)d_ws + 4096);
    float* ys0 = xi + (size_t)TSTEPS * LB * CO3;

    hipLaunchKernelGGL(zero_cnt_kernel, dim3(1), dim3(256), 0, stream, cnt);

    dim3 gxi(32, TSTEPS);

    // ---- layer 0 ----
    hipLaunchKernelGGL(xi_conv_kernel, gxi, dim3(256), 0, stream,
                       xs, (long)(TSTEPS * CIN), (long)CIN, Wi0, bi0, xi);
    {
        const float* Wh = Wh0; const float* xip = xi; float* yb = ys0;
        long yT = (long)LB * HDIM;   // ys0 (T,B,H)
        long bS = (long)HDIM;
        int* c0 = cnt;
        void* args[] = { (void*)&Wh, (void*)&xip, (void*)&yb,
                         (void*)&yT, (void*)&bS, (void*)&c0 };
        hipLaunchCooperativeKernel((void*)gru_seq_kernel, dim3(NBT * NJT),
                                   dim3(1024), args, 0, stream);
    }

    // ---- layer 1 ----
    hipLaunchKernelGGL(xi_conv_kernel, gxi, dim3(256), 0, stream,
                       ys0, (long)HDIM, (long)(LB * HDIM), Wi1, bi1, xi);
    {
        const float* Wh = Wh1; const float* xip = xi; float* yb = out;
        long yT = (long)HDIM;             // out (B,T,H): t slice offset = t*H
        long bS = (long)(TSTEPS * HDIM);  // b stride = T*H
        int* c1 = cnt + NBT * CNTSTR;
        void* args[] = { (void*)&Wh, (void*)&xip, (void*)&yb,
                         (void*)&yT, (void*)&bS, (void*)&c1 };
        hipLaunchCooperativeKernel((void*)gru_seq_kernel, dim3(NBT * NJT),
                                   dim3(1024), args, 0, stream);
    }
}